// Round 2
// baseline (297.289 us; speedup 1.0000x reference)
//
#include <hip/hip_runtime.h>
#include <hip/hip_bf16.h>
#include <cstdint>

using bf16 = __hip_bfloat16;
typedef __attribute__((ext_vector_type(8))) short short8;
typedef __attribute__((ext_vector_type(4))) float floatx4;

// Problem constants
static constexpr int BATCH = 8192;
static constexpr int K1    = 2304;   // OBS + NH
static constexpr int N1    = 2048;   // NH
static constexpr int K2    = 2048;   // NH
static constexpr int N2    = 256;    // 2*LAT

__device__ __forceinline__ void gload_lds16(const void* g, void* l) {
  __builtin_amdgcn_global_load_lds(
      (const __attribute__((address_space(1))) void*)g,
      (__attribute__((address_space(3))) void*)l, 16, 0, 0);
}

// tanh(x) = 1 - 2/(1+e^{2x}); exp2-based, saturates to +/-1, err ~1e-6
__device__ __forceinline__ float fast_tanh(float x) {
  float e = __builtin_amdgcn_exp2f(x * 2.8853900817779268f);  // 2*log2(e)
  return 1.0f - 2.0f * __builtin_amdgcn_rcpf(e + 1.0f);
}

// ---------------- converters (memory-bound, bf16x8 stores) ----------------
__global__ __launch_bounds__(256) void cvt_f32_to_bf16(
    const float* __restrict__ s, bf16* __restrict__ d, int n8) {
  int i = blockIdx.x * 256 + threadIdx.x;
  if (i >= n8) return;
  const float4* sp = (const float4*)s + (size_t)i * 2;
  float4 a = sp[0], b = sp[1];
  union { short8 v; bf16 e[8]; } u;
  u.e[0] = __float2bfloat16(a.x); u.e[1] = __float2bfloat16(a.y);
  u.e[2] = __float2bfloat16(a.z); u.e[3] = __float2bfloat16(a.w);
  u.e[4] = __float2bfloat16(b.x); u.e[5] = __float2bfloat16(b.y);
  u.e[6] = __float2bfloat16(b.z); u.e[7] = __float2bfloat16(b.w);
  *(short8*)(d + (size_t)i * 8) = u.v;
}

// fused cat(x,h) -> combined bf16 [8192 x 2304]; 288 16B-slots per row
__global__ __launch_bounds__(256) void build_combined(
    const float* __restrict__ x, const float* __restrict__ h,
    bf16* __restrict__ comb) {
  int i = blockIdx.x * 256 + threadIdx.x;   // exactly 8192*288 threads
  int row  = i / 288;
  int slot = i - row * 288;
  const float* src = (slot < 32) ? (x + (size_t)row * 256 + slot * 8)
                                 : (h + (size_t)row * 2048 + (slot - 32) * 8);
  float4 a = ((const float4*)src)[0];
  float4 b = ((const float4*)src)[1];
  union { short8 v; bf16 e[8]; } u;
  u.e[0] = __float2bfloat16(a.x); u.e[1] = __float2bfloat16(a.y);
  u.e[2] = __float2bfloat16(a.z); u.e[3] = __float2bfloat16(a.w);
  u.e[4] = __float2bfloat16(b.x); u.e[5] = __float2bfloat16(b.y);
  u.e[6] = __float2bfloat16(b.z); u.e[7] = __float2bfloat16(b.w);
  *(short8*)(comb + (size_t)row * 2304 + slot * 8) = u.v;
}

// out = bias broadcast (seed for gemm2's split-K atomic accumulation)
__global__ __launch_bounds__(256) void bias_init(
    const float* __restrict__ bias, float* __restrict__ out) {
  int i = blockIdx.x * 256 + threadIdx.x;   // 8192*64 threads, float4 each
  float4 b = ((const float4*)bias)[i & 63];
  ((float4*)out)[i] = b;
}

// ---------------- GEMM1: h_new = tanh(A @ W^T + bias) ----------------
// A [8192 x 2304] bf16 row-major, W [2048 x 2304] bf16 row-major (= B^T input)
// 128x128 tile, BK=64, 4 waves in 2x2, 64x64 per wave, 16x16x32 MFMA.
__global__ __launch_bounds__(256) void gemm1_tanh(
    const bf16* __restrict__ A, const bf16* __restrict__ W,
    const float* __restrict__ bias,
    float* __restrict__ hf32, bf16* __restrict__ hb16) {
  __shared__ bf16 As[128 * 64];
  __shared__ bf16 Bs[128 * 64];
  const int t    = threadIdx.x;
  const int lane = t & 63;
  const int wave = t >> 6;
  const int wm   = (wave & 1) * 64;
  const int wn   = (wave >> 1) * 64;
  const int quad = lane >> 4;
  const int r15  = lane & 15;
  const int srow = t >> 3;   // 0..31  staging row within 32-row group
  const int sc   = t & 7;    // 16B slot within row

  const size_t Abase = (size_t)blockIdx.x * 128 * K1;
  const size_t Bbase = (size_t)blockIdx.y * 128 * K1;

  floatx4 acc[4][4];
  const floatx4 z = {0.f, 0.f, 0.f, 0.f};
#pragma unroll
  for (int i = 0; i < 4; i++)
#pragma unroll
    for (int j = 0; j < 4; j++) acc[i][j] = z;

  for (int kt = 0; kt < K1 / 64; ++kt) {
    const int k0 = kt * 64;
    __syncthreads();
    // stage A-tile 128x64 (4 x 4KB issues), XOR-swizzled k-slot
#pragma unroll
    for (int it = 0; it < 4; ++it) {
      int row = it * 32 + srow;
      int gc  = k0 + ((sc ^ (row & 7)) << 3);
      gload_lds16(A + Abase + (size_t)row * K1 + gc,
                  (char*)As + it * 4096 + t * 16);
    }
#pragma unroll
    for (int it = 0; it < 4; ++it) {
      int row = it * 32 + srow;
      int gc  = k0 + ((sc ^ (row & 7)) << 3);
      gload_lds16(W + Bbase + (size_t)row * K1 + gc,
                  (char*)Bs + it * 4096 + t * 16);
    }
    __syncthreads();
#pragma unroll
    for (int ks = 0; ks < 2; ++ks) {
      short8 af[4], bfr[4];
      const int kq = ks * 4 + quad;
#pragma unroll
      for (int mt = 0; mt < 4; ++mt) {
        int row = wm + mt * 16 + r15;
        af[mt] = *(const short8*)((const char*)As + row * 128 +
                                  ((kq ^ (row & 7)) << 4));
      }
#pragma unroll
      for (int nt = 0; nt < 4; ++nt) {
        int row = wn + nt * 16 + r15;
        bfr[nt] = *(const short8*)((const char*)Bs + row * 128 +
                                   ((kq ^ (row & 7)) << 4));
      }
#pragma unroll
      for (int mt = 0; mt < 4; ++mt)
#pragma unroll
        for (int nt = 0; nt < 4; ++nt)
          acc[mt][nt] = __builtin_amdgcn_mfma_f32_16x16x32_bf16(
              af[mt], bfr[nt], acc[mt][nt], 0, 0, 0);
    }
  }

  // epilogue: bias + fast tanh, dual-write f32 (output) and bf16 (GEMM2 input)
  const int gcol0 = blockIdx.y * 128 + wn;
  float bv[4];
#pragma unroll
  for (int nt = 0; nt < 4; ++nt) bv[nt] = bias[gcol0 + nt * 16 + r15];
  const size_t grow0 = (size_t)blockIdx.x * 128 + wm;
#pragma unroll
  for (int mt = 0; mt < 4; ++mt) {
#pragma unroll
    for (int i = 0; i < 4; ++i) {
      size_t gr = grow0 + mt * 16 + quad * 4 + i;
      size_t rb = gr * (size_t)N1;
#pragma unroll
      for (int nt = 0; nt < 4; ++nt) {
        int gc = gcol0 + nt * 16 + r15;
        float v = fast_tanh(acc[mt][nt][i] + bv[nt]);
        hf32[rb + gc] = v;
        hb16[rb + gc] = __float2bfloat16(v);
      }
    }
  }
}

// ---------------- GEMM2 (split-K): out += h_new @ W_h2o^T ----------------
// A [8192 x 2048] bf16, W [256 x 2048] bf16. Tile 128x64, split-K=4
// -> grid 64 x 4 x 4 = 1024 blocks (4/CU). Each block does K-slice of 512
// (8 iters) and atomically accumulates f32 into out (pre-seeded with bias).
__global__ __launch_bounds__(256) void gemm2_splitk(
    const bf16* __restrict__ A, const bf16* __restrict__ W,
    float* __restrict__ out) {
  __shared__ bf16 As[128 * 64];
  __shared__ bf16 Bs[64 * 64];
  const int t    = threadIdx.x;
  const int lane = t & 63;
  const int wave = t >> 6;
  const int wm   = (wave & 1) * 64;
  const int wn   = (wave >> 1) * 32;
  const int quad = lane >> 4;
  const int r15  = lane & 15;
  const int srow = t >> 3;
  const int sc   = t & 7;

  const size_t Abase = (size_t)blockIdx.x * 128 * K2;
  const size_t Bbase = (size_t)blockIdx.y * 64 * K2;
  const int ks0 = blockIdx.z * (K2 / 4);   // 512-wide K slice

  floatx4 acc[4][2];
  const floatx4 z = {0.f, 0.f, 0.f, 0.f};
#pragma unroll
  for (int i = 0; i < 4; i++) { acc[i][0] = z; acc[i][1] = z; }

  for (int kt = 0; kt < 8; ++kt) {
    const int k0 = ks0 + kt * 64;
    __syncthreads();
#pragma unroll
    for (int it = 0; it < 4; ++it) {
      int row = it * 32 + srow;
      int gc  = k0 + ((sc ^ (row & 7)) << 3);
      gload_lds16(A + Abase + (size_t)row * K2 + gc,
                  (char*)As + it * 4096 + t * 16);
    }
#pragma unroll
    for (int it = 0; it < 2; ++it) {
      int row = it * 32 + srow;
      int gc  = k0 + ((sc ^ (row & 7)) << 3);
      gload_lds16(W + Bbase + (size_t)row * K2 + gc,
                  (char*)Bs + it * 4096 + t * 16);
    }
    __syncthreads();
#pragma unroll
    for (int ks = 0; ks < 2; ++ks) {
      short8 af[4], bfr[2];
      const int kq = ks * 4 + quad;
#pragma unroll
      for (int mt = 0; mt < 4; ++mt) {
        int row = wm + mt * 16 + r15;
        af[mt] = *(const short8*)((const char*)As + row * 128 +
                                  ((kq ^ (row & 7)) << 4));
      }
#pragma unroll
      for (int nt = 0; nt < 2; ++nt) {
        int row = wn + nt * 16 + r15;
        bfr[nt] = *(const short8*)((const char*)Bs + row * 128 +
                                   ((kq ^ (row & 7)) << 4));
      }
#pragma unroll
      for (int mt = 0; mt < 4; ++mt)
#pragma unroll
        for (int nt = 0; nt < 2; ++nt)
          acc[mt][nt] = __builtin_amdgcn_mfma_f32_16x16x32_bf16(
              af[mt], bfr[nt], acc[mt][nt], 0, 0, 0);
    }
  }

  const int gcol0 = blockIdx.y * 64 + wn;
  const size_t grow0 = (size_t)blockIdx.x * 128 + wm;
#pragma unroll
  for (int mt = 0; mt < 4; ++mt) {
#pragma unroll
    for (int i = 0; i < 4; ++i) {
      size_t gr = grow0 + mt * 16 + quad * 4 + i;
      size_t rb = gr * (size_t)N2;
#pragma unroll
      for (int nt = 0; nt < 2; ++nt) {
        int gc = gcol0 + nt * 16 + r15;
        unsafeAtomicAdd(&out[rb + gc], acc[mt][nt][i]);
      }
    }
  }
}

extern "C" void kernel_launch(void* const* d_in, const int* in_sizes, int n_in,
                              void* d_out, int out_size, void* d_ws,
                              size_t ws_size, hipStream_t stream) {
  const float* x     = (const float*)d_in[0];  // [8192, 256]
  const float* h     = (const float*)d_in[1];  // [8192, 2048]
  const float* W_i2h = (const float*)d_in[2];  // [2048, 2304]
  const float* b_i2h = (const float*)d_in[3];  // [2048]
  const float* W_h2o = (const float*)d_in[4];  // [256, 2048]
  const float* b_h2o = (const float*)d_in[5];  // [256]

  float* out       = (float*)d_out;                    // [8192, 256]
  float* hnew_f32  = out + (size_t)BATCH * N2;         // [8192, 2048]

  bf16* comb   = (bf16*)d_ws;                          // 8192*2304
  bf16* Wi2h_b = comb + (size_t)BATCH * K1;            // 2048*2304
  bf16* Wh2o_b = Wi2h_b + (size_t)N1 * K1;             // 256*2048
  bf16* hnew_b = Wh2o_b + (size_t)N2 * K2;             // 8192*2048

  // seed out with bias (before gemm2's atomic accumulation; stream-ordered)
  bias_init<<<(BATCH * N2 / 4) / 256, 256, 0, stream>>>(b_h2o, out);

  // converters
  build_combined<<<(BATCH * (K1 / 8)) / 256, 256, 0, stream>>>(x, h, comb);
  cvt_f32_to_bf16<<<((N1 * K1 / 8) + 255) / 256, 256, 0, stream>>>(
      W_i2h, Wi2h_b, N1 * K1 / 8);
  cvt_f32_to_bf16<<<((N2 * K2 / 8) + 255) / 256, 256, 0, stream>>>(
      W_h2o, Wh2o_b, N2 * K2 / 8);

  // GEMM1: grid 64 x 16 (M-tiles x N-tiles)
  gemm1_tanh<<<dim3(BATCH / 128, N1 / 128), 256, 0, stream>>>(
      comb, Wi2h_b, b_i2h, hnew_f32, hnew_b);

  // GEMM2: grid 64 x 4 x 4 (M x N x K-splits), atomic accumulate
  gemm2_splitk<<<dim3(BATCH / 128, N2 / 64, 4), 256, 0, stream>>>(
      hnew_b, Wh2o_b, out);
}

// Round 3
// 276.929 us; speedup vs baseline: 1.0735x; 1.0735x over previous
//
#include <hip/hip_runtime.h>
#include <hip/hip_bf16.h>
#include <cstdint>

using bf16 = __hip_bfloat16;
typedef __attribute__((ext_vector_type(8))) short short8;
typedef __attribute__((ext_vector_type(4))) float floatx4;

// Problem constants
static constexpr int BATCH = 8192;
static constexpr int K1    = 2304;   // OBS + NH
static constexpr int N1    = 2048;   // NH
static constexpr int K2    = 2048;   // NH
static constexpr int N2    = 256;    // 2*LAT

__device__ __forceinline__ void gload_lds16(const void* g, void* l) {
  __builtin_amdgcn_global_load_lds(
      (const __attribute__((address_space(1))) void*)g,
      (__attribute__((address_space(3))) void*)l, 16, 0, 0);
}

// tanh(x) = 1 - 2/(1+e^{2x}); exp2-based, saturates to +/-1, err ~1e-6
__device__ __forceinline__ float fast_tanh(float x) {
  float e = __builtin_amdgcn_exp2f(x * 2.8853900817779268f);  // 2*log2(e)
  return 1.0f - 2.0f * __builtin_amdgcn_rcpf(e + 1.0f);
}

__device__ __forceinline__ short8 cvt8(const float* src) {
  float4 a = ((const float4*)src)[0];
  float4 b = ((const float4*)src)[1];
  union { short8 v; bf16 e[8]; } u;
  u.e[0] = __float2bfloat16(a.x); u.e[1] = __float2bfloat16(a.y);
  u.e[2] = __float2bfloat16(a.z); u.e[3] = __float2bfloat16(a.w);
  u.e[4] = __float2bfloat16(b.x); u.e[5] = __float2bfloat16(b.y);
  u.e[6] = __float2bfloat16(b.z); u.e[7] = __float2bfloat16(b.w);
  return u.v;
}

// ---------------- fused prep: cat(x,h)->bf16, W_i2h->bf16, W_h2o->bf16 ----
// segment 0: 8192*288 slots (combined), seg 1: 2048*2304/8, seg 2: 256*2048/8
static constexpr int SEG0 = BATCH * (K1 / 8);          // 2,359,296
static constexpr int SEG1 = N1 * K1 / 8;               //   589,824
static constexpr int SEG2 = N2 * K2 / 8;               //    65,536
__global__ __launch_bounds__(256) void prep(
    const float* __restrict__ x, const float* __restrict__ h,
    const float* __restrict__ W1, const float* __restrict__ W2,
    bf16* __restrict__ comb, bf16* __restrict__ W1b, bf16* __restrict__ W2b) {
  int i = blockIdx.x * 256 + threadIdx.x;
  if (i < SEG0) {
    int row  = i / 288;
    int slot = i - row * 288;
    const float* src = (slot < 32) ? (x + (size_t)row * 256 + slot * 8)
                                   : (h + (size_t)row * 2048 + (slot - 32) * 8);
    *(short8*)(comb + (size_t)row * 2304 + slot * 8) = cvt8(src);
  } else if (i < SEG0 + SEG1) {
    int j = i - SEG0;
    *(short8*)(W1b + (size_t)j * 8) = cvt8(W1 + (size_t)j * 8);
  } else {
    int j = i - (SEG0 + SEG1);
    *(short8*)(W2b + (size_t)j * 8) = cvt8(W2 + (size_t)j * 8);
  }
}

// out = bias broadcast (seed for gemm2's split-K atomic accumulation)
__global__ __launch_bounds__(256) void bias_init(
    const float* __restrict__ bias, float* __restrict__ out) {
  int i = blockIdx.x * 256 + threadIdx.x;   // BATCH*64 threads, float4 each
  float4 b = ((const float4*)bias)[i & 63];
  ((float4*)out)[i] = b;
}

// ---------------- GEMM1: h_new = tanh(A @ W^T + bias) ----------------
// A [8192 x 2304] bf16 row-major, W [2048 x 2304] bf16 row-major (= B^T input)
// 128x128 tile, BK=64, 4 waves in 2x2, 64x64 per wave, 16x16x32 MFMA.
__global__ __launch_bounds__(256) void gemm1_tanh(
    const bf16* __restrict__ A, const bf16* __restrict__ W,
    const float* __restrict__ bias,
    float* __restrict__ hf32, bf16* __restrict__ hb16) {
  __shared__ bf16 As[128 * 64];
  __shared__ bf16 Bs[128 * 64];
  const int t    = threadIdx.x;
  const int lane = t & 63;
  const int wave = t >> 6;
  const int wm   = (wave & 1) * 64;
  const int wn   = (wave >> 1) * 64;
  const int quad = lane >> 4;
  const int r15  = lane & 15;
  const int srow = t >> 3;   // 0..31  staging row within 32-row group
  const int sc   = t & 7;    // 16B slot within row

  const size_t Abase = (size_t)blockIdx.x * 128 * K1;
  const size_t Bbase = (size_t)blockIdx.y * 128 * K1;

  floatx4 acc[4][4];
  const floatx4 z = {0.f, 0.f, 0.f, 0.f};
#pragma unroll
  for (int i = 0; i < 4; i++)
#pragma unroll
    for (int j = 0; j < 4; j++) acc[i][j] = z;

  for (int kt = 0; kt < K1 / 64; ++kt) {
    const int k0 = kt * 64;
    __syncthreads();
#pragma unroll
    for (int it = 0; it < 4; ++it) {
      int row = it * 32 + srow;
      int gc  = k0 + ((sc ^ (row & 7)) << 3);
      gload_lds16(A + Abase + (size_t)row * K1 + gc,
                  (char*)As + it * 4096 + t * 16);
    }
#pragma unroll
    for (int it = 0; it < 4; ++it) {
      int row = it * 32 + srow;
      int gc  = k0 + ((sc ^ (row & 7)) << 3);
      gload_lds16(W + Bbase + (size_t)row * K1 + gc,
                  (char*)Bs + it * 4096 + t * 16);
    }
    __syncthreads();
#pragma unroll
    for (int ks = 0; ks < 2; ++ks) {
      short8 af[4], bfr[4];
      const int kq = ks * 4 + quad;
#pragma unroll
      for (int mt = 0; mt < 4; ++mt) {
        int row = wm + mt * 16 + r15;
        af[mt] = *(const short8*)((const char*)As + row * 128 +
                                  ((kq ^ (row & 7)) << 4));
      }
#pragma unroll
      for (int nt = 0; nt < 4; ++nt) {
        int row = wn + nt * 16 + r15;
        bfr[nt] = *(const short8*)((const char*)Bs + row * 128 +
                                   ((kq ^ (row & 7)) << 4));
      }
#pragma unroll
      for (int mt = 0; mt < 4; ++mt)
#pragma unroll
        for (int nt = 0; nt < 4; ++nt)
          acc[mt][nt] = __builtin_amdgcn_mfma_f32_16x16x32_bf16(
              af[mt], bfr[nt], acc[mt][nt], 0, 0, 0);
    }
  }

  // epilogue: bias + fast tanh, dual-write f32 (output) and bf16 (GEMM2 input)
  const int gcol0 = blockIdx.y * 128 + wn;
  float bv[4];
#pragma unroll
  for (int nt = 0; nt < 4; ++nt) bv[nt] = bias[gcol0 + nt * 16 + r15];
  const size_t grow0 = (size_t)blockIdx.x * 128 + wm;
#pragma unroll
  for (int mt = 0; mt < 4; ++mt) {
#pragma unroll
    for (int i = 0; i < 4; ++i) {
      size_t gr = grow0 + mt * 16 + quad * 4 + i;
      size_t rb = gr * (size_t)N1;
#pragma unroll
      for (int nt = 0; nt < 4; ++nt) {
        int gc = gcol0 + nt * 16 + r15;
        float v = fast_tanh(acc[mt][nt][i] + bv[nt]);
        hf32[rb + gc] = v;
        hb16[rb + gc] = __float2bfloat16(v);
      }
    }
  }
}

// ---------------- GEMM2: out += h_new @ W_h2o^T (split-K=2) -------------
// A [8192 x 2048] bf16, W [256 x 2048] bf16. Tile 32 x 256 (full N2),
// grid (256 M-tiles, 2 K-splits) = 512 blocks. Each A row is read exactly
// once across the grid; W (1 MB) stays L2-resident. 4 waves, each wave
// covers 32 rows x 64 cols (2x4 fragments). Atomic f32 accumulate into
// out pre-seeded with bias.
__global__ __launch_bounds__(256) void gemm2_out(
    const bf16* __restrict__ A, const bf16* __restrict__ W,
    float* __restrict__ out) {
  __shared__ bf16 As[32 * 64];    //  4 KB
  __shared__ bf16 Bs[256 * 64];   // 32 KB
  const int t    = threadIdx.x;
  const int lane = t & 63;
  const int wave = t >> 6;
  const int quad = lane >> 4;
  const int r15  = lane & 15;
  const int srow = t >> 3;   // 0..31
  const int sc   = t & 7;

  const int mrow0 = blockIdx.x * 32;
  const int kbase = blockIdx.y * (K2 / 2);   // 0 or 1024

  floatx4 acc[2][4];
  const floatx4 z = {0.f, 0.f, 0.f, 0.f};
#pragma unroll
  for (int i = 0; i < 2; i++)
#pragma unroll
    for (int j = 0; j < 4; j++) acc[i][j] = z;

  for (int kt = 0; kt < 16; ++kt) {
    const int k0 = kbase + kt * 64;
    __syncthreads();
    {  // A tile: 32 rows x 64 cols = one 16B issue per thread
      int row = srow;
      int gc  = k0 + ((sc ^ (row & 7)) << 3);
      gload_lds16(A + (size_t)(mrow0 + row) * K2 + gc, (char*)As + t * 16);
    }
#pragma unroll
    for (int it = 0; it < 8; ++it) {  // W tile: 256 rows x 64 cols
      int row = it * 32 + srow;
      int gc  = k0 + ((sc ^ (row & 7)) << 3);
      gload_lds16(W + (size_t)row * K2 + gc,
                  (char*)Bs + it * 4096 + t * 16);
    }
    __syncthreads();
#pragma unroll
    for (int ks = 0; ks < 2; ++ks) {
      short8 af[2], bfr[4];
      const int kq = ks * 4 + quad;
#pragma unroll
      for (int mt = 0; mt < 2; ++mt) {
        int row = mt * 16 + r15;
        af[mt] = *(const short8*)((const char*)As + row * 128 +
                                  ((kq ^ (row & 7)) << 4));
      }
#pragma unroll
      for (int nt = 0; nt < 4; ++nt) {
        int row = wave * 64 + nt * 16 + r15;
        bfr[nt] = *(const short8*)((const char*)Bs + row * 128 +
                                   ((kq ^ (row & 7)) << 4));
      }
#pragma unroll
      for (int mt = 0; mt < 2; ++mt)
#pragma unroll
        for (int nt = 0; nt < 4; ++nt)
          acc[mt][nt] = __builtin_amdgcn_mfma_f32_16x16x32_bf16(
              af[mt], bfr[nt], acc[mt][nt], 0, 0, 0);
    }
  }

  const int gcol0 = wave * 64;
#pragma unroll
  for (int mt = 0; mt < 2; ++mt) {
#pragma unroll
    for (int i = 0; i < 4; ++i) {
      size_t gr = (size_t)mrow0 + mt * 16 + quad * 4 + i;
      size_t rb = gr * (size_t)N2;
#pragma unroll
      for (int nt = 0; nt < 4; ++nt) {
        int gc = gcol0 + nt * 16 + r15;
        unsafeAtomicAdd(&out[rb + gc], acc[mt][nt][i]);
      }
    }
  }
}

extern "C" void kernel_launch(void* const* d_in, const int* in_sizes, int n_in,
                              void* d_out, int out_size, void* d_ws,
                              size_t ws_size, hipStream_t stream) {
  const float* x     = (const float*)d_in[0];  // [8192, 256]
  const float* h     = (const float*)d_in[1];  // [8192, 2048]
  const float* W_i2h = (const float*)d_in[2];  // [2048, 2304]
  const float* b_i2h = (const float*)d_in[3];  // [2048]
  const float* W_h2o = (const float*)d_in[4];  // [256, 2048]
  const float* b_h2o = (const float*)d_in[5];  // [256]

  float* out       = (float*)d_out;                    // [8192, 256]
  float* hnew_f32  = out + (size_t)BATCH * N2;         // [8192, 2048]

  bf16* comb   = (bf16*)d_ws;                          // 8192*2304
  bf16* Wi2h_b = comb + (size_t)BATCH * K1;            // 2048*2304
  bf16* Wh2o_b = Wi2h_b + (size_t)N1 * K1;             // 256*2048
  bf16* hnew_b = Wh2o_b + (size_t)N2 * K2;             // 8192*2048

  // seed out with bias (before gemm2's atomic accumulation; stream-ordered)
  bias_init<<<(BATCH * N2 / 4) / 256, 256, 0, stream>>>(b_h2o, out);

  // fused converters
  prep<<<(SEG0 + SEG1 + SEG2) / 256, 256, 0, stream>>>(
      x, h, W_i2h, W_h2o, comb, Wi2h_b, Wh2o_b);

  // GEMM1: grid 64 x 16 (M-tiles x N-tiles)
  gemm1_tanh<<<dim3(BATCH / 128, N1 / 128), 256, 0, stream>>>(
      comb, Wi2h_b, b_i2h, hnew_f32, hnew_b);

  // GEMM2: grid 256 x 2 (M-tiles x K-splits), atomic accumulate
  gemm2_out<<<dim3(BATCH / 32, 2), 256, 0, stream>>>(hnew_b, Wh2o_b, out);
}